// Round 6
// baseline (528.825 us; speedup 1.0000x reference)
//
#include <hip/hip_runtime.h>
#include <hip/hip_bf16.h>

#define B_SZ 8192
#define DIMS 1024
#define CLN 8
#define BM 128
#define PADMAX (B_SZ + CLN * BM)     // 9216
#define MAX_TILES (B_SZ / BM + CLN)  // 72

typedef __attribute__((ext_vector_type(8))) __bf16 bf16x8;
typedef __attribute__((ext_vector_type(8))) short short8;
typedef __attribute__((ext_vector_type(4))) short short4v;
typedef __attribute__((ext_vector_type(4))) float f32x4;

__device__ __forceinline__ short f2bf(float f) {
  __hip_bfloat16 h = __float2bfloat16(f);
  return __builtin_bit_cast(short, h);
}
__device__ __forceinline__ float bf2f(short s) {
  unsigned u = ((unsigned)(unsigned short)s) << 16;
  return __builtin_bit_cast(float, u);
}

// async 16B/lane global->LDS DMA. LDS dest is wave-uniform base; HW adds lane*16.
__device__ __forceinline__ void gl_lds16(const void* g, void* l) {
  __builtin_amdgcn_global_load_lds(
      (const __attribute__((address_space(1))) unsigned int*)(unsigned long long)(uintptr_t)g,
      (__attribute__((address_space(3))) unsigned int*)(unsigned long long)(uintptr_t)l,
      16, 0, 0);
}

// ---- router: 4 waves/block, 1 sample/wave, fused fp32->bf16 of x ----
__global__ void __launch_bounds__(256, 4)
router_kernel(const float* __restrict__ x, const float* __restrict__ center,
              int* __restrict__ router, short* __restrict__ xb) {
  const int bx = blockIdx.x;
  const int tid = threadIdx.x;
  const int lane = tid & 63;
  const int w = tid >> 6;
  const int s = bx * 4 + w;
  const float4* xr = (const float4*)(x + (size_t)s * DIMS);
  float4 xv[4];
#pragma unroll
  for (int j = 0; j < 4; ++j) xv[j] = xr[j * 64 + lane];
  if (xb) {
    short* xbr = xb + (size_t)s * DIMS;
#pragma unroll
    for (int j = 0; j < 4; ++j) {
      short4v sv;
      sv[0] = f2bf(xv[j].x); sv[1] = f2bf(xv[j].y);
      sv[2] = f2bf(xv[j].z); sv[3] = f2bf(xv[j].w);
      *(short4v*)(xbr + j * 256 + lane * 4) = sv;
    }
  }
  float p[CLN];
#pragma unroll
  for (int c = 0; c < CLN; ++c) p[c] = 0.f;
#pragma unroll
  for (int j = 0; j < 4; ++j) {
    float4 cv[CLN];
#pragma unroll
    for (int c = 0; c < CLN; ++c)
      cv[c] = ((const float4*)(center + (size_t)c * DIMS))[j * 64 + lane];
#pragma unroll
    for (int c = 0; c < CLN; ++c)
      p[c] += xv[j].x * cv[c].x + xv[j].y * cv[c].y + xv[j].z * cv[c].z + xv[j].w * cv[c].w;
  }
#pragma unroll
  for (int c = 0; c < CLN; ++c) {
#pragma unroll
    for (int m = 1; m < 64; m <<= 1) p[c] += __shfl_xor(p[c], m);
  }
  if (lane == 0) {
    int best = 0; float bv = p[0];
#pragma unroll
    for (int c = 1; c < CLN; ++c) { if (p[c] > bv) { bv = p[c]; best = c; } }
    router[s] = best;
  }
}

// ---- mono-block counting sort + zero z ----
__global__ void sort_kernel(const int* __restrict__ router, int* __restrict__ counts,
                            int* __restrict__ pstart, int* __restrict__ meta,
                            int* __restrict__ tile_c, int* __restrict__ tile_r,
                            int* __restrict__ order, float* __restrict__ z) {
  __shared__ int bins[CLN];
  __shared__ int cur[CLN];
  __shared__ int ps_s[CLN + 1];
  const int t = threadIdx.x;
  const int lane = t & 63;
  for (int p = t; p < PADMAX; p += 1024) z[p] = 0.f;   // gemm2 dot-accumulator
  if (t < CLN) bins[t] = 0;
  __syncthreads();
  int myc[8];
#pragma unroll
  for (int j = 0; j < 8; ++j) myc[j] = router[t + 1024 * j];
#pragma unroll
  for (int j = 0; j < 8; ++j) {
#pragma unroll
    for (int c = 0; c < CLN; ++c) {
      unsigned long long m = __ballot(myc[j] == c);
      if (lane == 0 && m) atomicAdd(&bins[c], __popcll(m));
    }
  }
  __syncthreads();
  if (t == 0) {
    int ps = 0, nt = 0;
    for (int c = 0; c < CLN; ++c) {
      const int tot = bins[c];
      counts[c] = tot; pstart[c] = ps; ps_s[c] = ps; cur[c] = 0;
      const int tiles = (tot + BM - 1) / BM;
      for (int i = 0; i < tiles; ++i) { tile_c[nt] = c; tile_r[nt] = ps + i * BM; ++nt; }
      ps += tiles * BM;
    }
    pstart[CLN] = ps; ps_s[CLN] = ps; meta[0] = nt; meta[1] = ps;
  }
  __syncthreads();
#pragma unroll
  for (int j = 0; j < 8; ++j) {
    const int s = t + 1024 * j;
    const int c = myc[j];
    int pos = 0;
#pragma unroll
    for (int cc = 0; cc < CLN; ++cc) {
      unsigned long long m = __ballot(c == cc);
      int b = 0;
      if (lane == 0 && m) b = atomicAdd(&cur[cc], __popcll(m));
      b = __shfl(b, 0);
      if (c == cc) pos = ps_s[cc] + b + __popcll(m & ((1ull << lane) - 1ull));
    }
    order[pos] = s;
  }
  __syncthreads();
  for (int p = t; p < PADMAX; p += 1024) {
#pragma unroll
    for (int c = 0; c < CLN; ++c) {
      if (p >= ps_s[c] && p < ps_s[c + 1]) {
        if (p - ps_s[c] >= bins[c]) order[p] = order[ps_s[c]];
        break;
      }
    }
  }
}

// -------- fused-gate GEMM (round-10) --------
// 128x128 tile, 4 waves, BK=32, mfma_f32_16x16x32_bf16 — MFMA/A-side/epilogue
// identical to the proven gemm_async. The B side no longer reads a
// pre-materialized gwt: per k-step it DMAs the fp32 w0/wc [32k x 128n] panels
// (contiguous 512B rows — no global transpose anywhere) into LDS, then a gate
// phase computes bf16(w0*wc) and writes the transposed Bs[n][k] (stride 40,
// gemm_layer-proven frag layout). Eliminates the entire prep gate (~75us at an
// unfixable 2.2 TB/s) and 151 MB of gwt HBM write+read traffic. fp32 panel
// re-reads (~9 same-panel blocks) are L2-local: same-panel blocks are NT==0
// mod 8 apart -> same XCD; unique weights are L3-resident.
template <int K, int N, bool GATHER, bool FUSE_DOT>
__global__ void gemm_fused(const short* __restrict__ Abase,
                           const float* __restrict__ w0g, const float* __restrict__ wcg,
                           short* __restrict__ Aout, const int* __restrict__ order,
                           const int* __restrict__ tile_c, const int* __restrict__ tile_r,
                           const int* __restrict__ meta,
                           const float* __restrict__ w03, const float* __restrict__ wc3,
                           float* __restrict__ z) {
  constexpr int NT = N / 128;
  const int bt = blockIdx.x / NT;
  if (bt >= meta[0]) return;
  const int n0 = (blockIdx.x % NT) * 128;
  const int cl = tile_c[bt];
  const int row0 = tile_r[bt];

  __shared__ __align__(16) short As[128 * 32];   // 8 KB
  __shared__ __align__(16) short Bs[128 * 40];   // 10 KB (stride 40: bank spread)
  __shared__ __align__(16) float Fw[32 * 128];   // 16 KB fp32 w0 panel
  __shared__ __align__(16) float Fc[32 * 128];   // 16 KB fp32 wc panel

  const int tid = threadIdx.x;
  const int lane = tid & 63;
  const int w = tid >> 6;
  const int wm = w >> 1;
  const int wn = w & 1;

  // A staging (unchanged)
  const int lrow = lane >> 2;
  const int kofs = (lane & 3) << 3;
  const short* ga0;
  const short* ga1;
  if (GATHER) {
    ga0 = Abase + (size_t)order[row0 + w * 16 + lrow] * K + kofs;
    ga1 = Abase + (size_t)order[row0 + 64 + w * 16 + lrow] * K + kofs;
  } else {
    ga0 = Abase + (size_t)(row0 + w * 16 + lrow) * K + kofs;
    ga1 = ga0 + (size_t)64 * K;
  }
  short* lA0 = &As[w * 16 * 32];
  short* lA1 = &As[(64 + w * 16) * 32];

  // B fp32 panel staging: wave w stages rows w*8..w*8+7 of the [32][128] tile,
  // 2 rows per DMA (lanes 0-31 -> row r, lanes 32-63 -> row r+1; LDS linear).
  const int brow = lane >> 5;
  const int bcol = (lane & 31) * 4;
  const float* gw = w0g + n0 + bcol;
  const float* gc = wcg + (size_t)cl * K * N + n0 + bcol;

  // gate-transpose mapping: thread = 2 consecutive n x 8 consecutive k
  const int n2 = (tid & 63) * 2;
  const int kh = (tid >> 6) * 8;

  f32x4 acc[4][4] = {};
  const int arL = wm * 64 + (lane & 15);
  const int bcL = wn * 64 + (lane & 15);
  const int kq = (lane >> 4) << 3;

  for (int kb = 0; kb < K; kb += 32) {
    __syncthreads();
    gl_lds16(ga0 + kb, lA0);
    gl_lds16(ga1 + kb, lA1);
#pragma unroll
    for (int j = 0; j < 4; ++j) {
      const int r2 = w * 8 + j * 2;
      const size_t go = (size_t)(kb + r2 + brow) * N;
      gl_lds16(gw + go, &Fw[r2 * 128]);
      gl_lds16(gc + go, &Fc[r2 * 128]);
    }
    __syncthreads();
    // gate + transpose: Bs[n][k] = bf16(Fw[k][n] * Fc[k][n])
    short8 o0, o1;
#pragma unroll
    for (int dk = 0; dk < 8; ++dk) {
      const float2 a = *(const float2*)&Fw[(kh + dk) * 128 + n2];
      const float2 b = *(const float2*)&Fc[(kh + dk) * 128 + n2];
      o0[dk] = f2bf(a.x * b.x);
      o1[dk] = f2bf(a.y * b.y);
    }
    *(short8*)&Bs[n2 * 40 + kh] = o0;
    *(short8*)&Bs[(n2 + 1) * 40 + kh] = o1;
    __syncthreads();

    short8 af[4], bfr[4];
#pragma unroll
    for (int mi = 0; mi < 4; ++mi) af[mi] = *(const short8*)&As[(arL + mi * 16) * 32 + kq];
#pragma unroll
    for (int ni = 0; ni < 4; ++ni) bfr[ni] = *(const short8*)&Bs[(bcL + ni * 16) * 40 + kq];
#pragma unroll
    for (int mi = 0; mi < 4; ++mi) {
#pragma unroll
      for (int ni = 0; ni < 4; ++ni) {
        acc[mi][ni] = __builtin_amdgcn_mfma_f32_16x16x32_bf16(
            __builtin_bit_cast(bf16x8, af[mi]), __builtin_bit_cast(bf16x8, bfr[ni]),
            acc[mi][ni], 0, 0, 0);
      }
    }
  }

  // C/D layout: col=lane&15, row=(lane>>4)*4+reg
  const int er = (lane >> 4) << 2;
  const int ec = lane & 15;
  if constexpr (FUSE_DOT) {
    float g[4];
#pragma unroll
    for (int ni = 0; ni < 4; ++ni) {
      const int col = n0 + wn * 64 + ni * 16 + ec;
      g[ni] = w03[col] * wc3[cl * N + col];
    }
#pragma unroll
    for (int mi = 0; mi < 4; ++mi) {
#pragma unroll
      for (int r = 0; r < 4; ++r) {
        float v = 0.f;
#pragma unroll
        for (int ni = 0; ni < 4; ++ni) v += fmaxf(acc[mi][ni][r], 0.f) * g[ni];
#pragma unroll
        for (int m = 1; m < 16; m <<= 1) v += __shfl_xor(v, m);
        if ((lane & 15) == 0)
          atomicAdd(&z[row0 + wm * 64 + mi * 16 + er + r], v);
      }
    }
  } else {
#pragma unroll
    for (int mi = 0; mi < 4; ++mi) {
#pragma unroll
      for (int ni = 0; ni < 4; ++ni) {
#pragma unroll
        for (int r = 0; r < 4; ++r) {
          float vv = fmaxf(acc[mi][ni][r], 0.f);
          const int row = row0 + wm * 64 + mi * 16 + er + r;
          const int col = n0 + wn * 64 + ni * 16 + ec;
          Aout[(size_t)row * N + col] = f2bf(vv);
        }
      }
    }
  }
}

// sigmoid + scatter to original sample slots
__global__ void final_kernel(const float* __restrict__ z, const int* __restrict__ order,
                             const int* __restrict__ meta, float* __restrict__ out) {
  const int r = blockIdx.x * 256 + threadIdx.x;
  if (r < meta[1]) out[order[r]] = 1.f / (1.f + expf(-z[r]));
}

// -------- fallback GEMM (round-1): gating fused in staging, fp32 weights --------
template <int K, int N, bool GATHER>
__global__ void gemm_layer(const float* __restrict__ Xf, const short* __restrict__ Ain,
                           const float* __restrict__ w0, const float* __restrict__ wc,
                           short* __restrict__ Aout,
                           const int* __restrict__ order,
                           const int* __restrict__ tile_c, const int* __restrict__ tile_r,
                           const int* __restrict__ meta) {
  const int bt = blockIdx.x;
  if (bt >= meta[0]) return;
  const int cl = tile_c[bt];
  const int row0 = tile_r[bt];
  const int n0 = blockIdx.y * 128;

  __shared__ __align__(16) short As[128 * 40];
  __shared__ __align__(16) short Bs[128 * 40];

  const int tid = threadIdx.x;
  const int lane = tid & 63;
  const int wm = (tid >> 6) >> 1;
  const int wn = (tid >> 6) & 1;

  f32x4 acc[4][4] = {};

  const int arow = tid >> 2;
  const int akseg = (tid & 3) << 3;
  const int bn = tid & 127;
  const int bkq = (tid >> 7) << 3;

  const float* xr0 = nullptr; const float* xr1 = nullptr;
  const short* ar0 = nullptr; const short* ar1 = nullptr;
  if (GATHER) {
    xr0 = Xf + (size_t)order[row0 + arow] * K + akseg;
    xr1 = Xf + (size_t)order[row0 + arow + 64] * K + akseg;
  } else {
    ar0 = Ain + (size_t)(row0 + arow) * K + akseg;
    ar1 = Ain + (size_t)(row0 + arow + 64) * K + akseg;
  }
  const float* w0p = w0 + n0 + bn;
  const float* wcp = wc + (size_t)cl * K * N + n0 + bn;

  for (int kb = 0; kb < K; kb += 32) {
    __syncthreads();
    if (GATHER) {
      float4 a = *(const float4*)(xr0 + kb);
      float4 b = *(const float4*)(xr0 + kb + 4);
      short8 v;
      v[0] = f2bf(a.x); v[1] = f2bf(a.y); v[2] = f2bf(a.z); v[3] = f2bf(a.w);
      v[4] = f2bf(b.x); v[5] = f2bf(b.y); v[6] = f2bf(b.z); v[7] = f2bf(b.w);
      *(short8*)&As[arow * 40 + akseg] = v;
      a = *(const float4*)(xr1 + kb);
      b = *(const float4*)(xr1 + kb + 4);
      v[0] = f2bf(a.x); v[1] = f2bf(a.y); v[2] = f2bf(a.z); v[3] = f2bf(a.w);
      v[4] = f2bf(b.x); v[5] = f2bf(b.y); v[6] = f2bf(b.z); v[7] = f2bf(b.w);
      *(short8*)&As[(arow + 64) * 40 + akseg] = v;
    } else {
      *(short8*)&As[arow * 40 + akseg] = *(const short8*)(ar0 + kb);
      *(short8*)&As[(arow + 64) * 40 + akseg] = *(const short8*)(ar1 + kb);
    }
#pragma unroll
    for (int half = 0; half < 2; ++half) {
      const int kk = bkq + half * 16;
      short8 v;
#pragma unroll
      for (int j = 0; j < 8; ++j) {
        const size_t off = (size_t)(kb + kk + j) * N;
        v[j] = f2bf(w0p[off] * wcp[off]);
      }
      *(short8*)&Bs[bn * 40 + kk] = v;
    }
    __syncthreads();

    const int arL = wm * 64 + (lane & 15);
    const int kq = (lane >> 4) << 3;
    const int bcL = wn * 64 + (lane & 15);
    short8 af[4], bfr[4];
#pragma unroll
    for (int mi = 0; mi < 4; ++mi) af[mi] = *(const short8*)&As[(arL + mi * 16) * 40 + kq];
#pragma unroll
    for (int ni = 0; ni < 4; ++ni) bfr[ni] = *(const short8*)&Bs[(bcL + ni * 16) * 40 + kq];
#pragma unroll
    for (int mi = 0; mi < 4; ++mi) {
#pragma unroll
      for (int ni = 0; ni < 4; ++ni) {
        acc[mi][ni] = __builtin_amdgcn_mfma_f32_16x16x32_bf16(
            __builtin_bit_cast(bf16x8, af[mi]), __builtin_bit_cast(bf16x8, bfr[ni]),
            acc[mi][ni], 0, 0, 0);
      }
    }
  }

  const int er = (lane >> 4) << 2;
  const int ec = lane & 15;
#pragma unroll
  for (int mi = 0; mi < 4; ++mi) {
#pragma unroll
    for (int ni = 0; ni < 4; ++ni) {
#pragma unroll
      for (int r = 0; r < 4; ++r) {
        float vv = fmaxf(acc[mi][ni][r], 0.f);
        const int row = row0 + wm * 64 + mi * 16 + er + r;
        const int col = n0 + wn * 64 + ni * 16 + ec;
        Aout[(size_t)row * N + col] = f2bf(vv);
      }
    }
  }
}

// fallback final layer (reads h2 bf16)
__global__ void layer3_kernel(const short* __restrict__ h2, const float* __restrict__ w03,
                              const float* __restrict__ wc3, const int* __restrict__ order,
                              const int* __restrict__ pstart, const int* __restrict__ meta,
                              float* __restrict__ out) {
  const int tid = threadIdx.x;
  const int lane = tid & 63;
  const int w = tid >> 6;
  const int r = blockIdx.x * 4 + w;
  if (r >= meta[1]) return;
  int c = 0;
#pragma unroll
  for (int i = 1; i < CLN; ++i) { if (r >= pstart[i]) c = i; }
  const short* hr = h2 + (size_t)r * 512;
  const int k0 = lane * 8;
  const short8 hv = *(const short8*)(hr + k0);
  const float* wcr = wc3 + c * 512;
  float part = 0.f;
#pragma unroll
  for (int j = 0; j < 8; ++j) part += bf2f(hv[j]) * w03[k0 + j] * wcr[k0 + j];
  for (int off = 32; off; off >>= 1) part += __shfl_down(part, off);
  if (lane == 0) out[order[r]] = 1.f / (1.f + expf(-part));
}

extern "C" void kernel_launch(void* const* d_in, const int* in_sizes, int n_in,
                              void* d_out, int out_size, void* d_ws, size_t ws_size,
                              hipStream_t stream) {
  const float* x = (const float*)d_in[0];
  const float* center = (const float*)d_in[1];
  const float* w0s[4]; const float* wcs[4];
  if (in_sizes[3] == 8 * in_sizes[2]) {  // dict order: w0_i, wc_i interleaved
    for (int i = 0; i < 4; ++i) { w0s[i] = (const float*)d_in[2 + 2 * i]; wcs[i] = (const float*)d_in[3 + 2 * i]; }
  } else {                               // signature order: w0_0..w0_3, wc_0..wc_3
    for (int i = 0; i < 4; ++i) { w0s[i] = (const float*)d_in[2 + i]; wcs[i] = (const float*)d_in[6 + i]; }
  }
  float* out = (float*)d_out;
  char* ws = (char*)d_ws;
  int* counts = (int*)(ws + 0);      // 8
  int* pstart = (int*)(ws + 128);    // 9
  int* meta   = (int*)(ws + 192);    // 2
  int* tile_c = (int*)(ws + 256);    // 72
  int* tile_r = (int*)(ws + 1024);   // 72
  int* router = (int*)(ws + 4096);   // 8192 ints
  int* order  = (int*)(ws + 4096 + 4 * B_SZ);         // 9216 ints
  float* z    = (float*)(ws + 4096 + 4 * B_SZ + 4 * PADMAX);  // 9216 floats, ends < 131072

  const size_t H0B = (size_t)PADMAX * 2048 * 2;       // 37.75 MB
  const size_t H1B = (size_t)PADMAX * 1024 * 2;       // 18.87 MB (>= xb 16.8 MB)
  const size_t NEED_F = 131072 + H0B + H1B;           // ~56.8 MB

  if (ws_size >= NEED_F) {
    short* h0 = (short*)(ws + 131072);
    short* h1 = (short*)(ws + 131072 + H0B);
    short* xb = h1;   // xb lives router->gemm0; h1 lives gemm1->gemm2 (disjoint)

    router_kernel<<<2048, 256, 0, stream>>>(x, center, router, xb);
    sort_kernel<<<1, 1024, 0, stream>>>(router, counts, pstart, meta, tile_c, tile_r, order, z);
    gemm_fused<1024, 2048, true, false><<<MAX_TILES * 16, 256, 0, stream>>>(
        xb, w0s[0], wcs[0], h0, order, tile_c, tile_r, meta, nullptr, nullptr, nullptr);
    gemm_fused<2048, 1024, false, false><<<MAX_TILES * 8, 256, 0, stream>>>(
        h0, w0s[1], wcs[1], h1, order, tile_c, tile_r, meta, nullptr, nullptr, nullptr);
    gemm_fused<1024, 512, false, true><<<MAX_TILES * 4, 256, 0, stream>>>(
        h1, w0s[2], wcs[2], nullptr, order, tile_c, tile_r, meta, w0s[3], wcs[3], z);
    final_kernel<<<PADMAX / 256, 256, 0, stream>>>(z, order, meta, out);
  } else {
    short* f0 = (short*)(ws + 131072);
    short* f1 = f0 + (size_t)PADMAX * 2048;
    short* f2 = f1 + (size_t)PADMAX * 1024;
    router_kernel<<<2048, 256, 0, stream>>>(x, center, router, nullptr);
    sort_kernel<<<1, 1024, 0, stream>>>(router, counts, pstart, meta, tile_c, tile_r, order, z);
    gemm_layer<1024, 2048, true><<<dim3(MAX_TILES, 16), 256, 0, stream>>>(
        x, nullptr, w0s[0], wcs[0], f0, order, tile_c, tile_r, meta);
    gemm_layer<2048, 1024, false><<<dim3(MAX_TILES, 8), 256, 0, stream>>>(
        nullptr, f0, w0s[1], wcs[1], f1, order, tile_c, tile_r, meta);
    gemm_layer<1024, 512, false><<<dim3(MAX_TILES, 4), 256, 0, stream>>>(
        nullptr, f1, w0s[2], wcs[2], f2, order, tile_c, tile_r, meta);
    layer3_kernel<<<(PADMAX + 3) / 4, 256, 0, stream>>>(f2, w0s[3], wcs[3], order, pstart, meta, out);
  }
}